// Round 19
// baseline (790.513 us; speedup 1.0000x reference)
//
#include <hip/hip_runtime.h>

// RGCN: 2-layer hetero GraphConv, R=4 relations.
// R12 (738): CSR+rank atomic-free fill, scan||norm, half-wave gathers.
// R14 (699): hist ILP, single-pass gemm1. R16 (688): quarter-wave gather2.
// R17 (675): gemm2 BN=256, fill x4. gather1 AT bandwidth product.
// R18: fused layer-1 RETRY with occupancy fix — BM=64 nodes, LDS 33.8KB ->
// 4 blocks/CU (32 waves, vs R13's 2 blocks/16 waves that regressed), forced
// VGPR<=64 via __launch_bounds__(512,8). Kills the 460MB agg4 round-trip.

#define RELS 4
#define DIN 256
#define DHID 256
#define DOUT 128
#define LDP 264   // padded LDS row stride (bf16); 33 16B-chunks/row (odd -> 2-way-free)

typedef short short8 __attribute__((ext_vector_type(8)));
typedef unsigned short ushort8 __attribute__((ext_vector_type(8)));
typedef float f32x4 __attribute__((ext_vector_type(4)));
typedef unsigned int uint4v __attribute__((ext_vector_type(4)));

// ---- helpers --------------------------------------------------------------

__device__ __forceinline__ unsigned short f2bf(float f) {
    unsigned int u = __float_as_uint(f);
    u += 0x7FFFu + ((u >> 16) & 1u);   // round-to-nearest-even
    return (unsigned short)(u >> 16);
}
__device__ __forceinline__ unsigned int cvt_pk_bf16(float lo, float hi) {
    unsigned int r;
    asm("v_cvt_pk_bf16_f32 %0, %1, %2" : "=v"(r) : "v"(lo), "v"(hi));
    return r;
}

// ---- CSR build --------------------------------------------------------------

// 4 edges per thread (int4 loads, 8 atomics in flight). Rank = dst-atomic's
// return value = unique slot in (rel,dst) segment (order-independent).
__global__ void hist_kernel(const int* __restrict__ src, const int* __restrict__ dst,
                            int* __restrict__ cnt_src, int* __restrict__ cnt_dst,
                            int* __restrict__ rank, int E, int N) {
    int i = blockIdx.x * blockDim.x + threadIdx.x;
    int j = i * 4;
    if (j >= RELS * E) return;
    int4 sv = *(const int4*)(src + j);
    int4 dv = *(const int4*)(dst + j);
    int r0 = j / E, r1 = (j + 1) / E, r2 = (j + 2) / E, r3 = (j + 3) / E;
    atomicAdd(cnt_src + (size_t)r0 * N + sv.x, 1);
    atomicAdd(cnt_src + (size_t)r1 * N + sv.y, 1);
    atomicAdd(cnt_src + (size_t)r2 * N + sv.z, 1);
    atomicAdd(cnt_src + (size_t)r3 * N + sv.w, 1);
    int rk0 = atomicAdd(cnt_dst + (size_t)r0 * N + dv.x, 1);
    int rk1 = atomicAdd(cnt_dst + (size_t)r1 * N + dv.y, 1);
    int rk2 = atomicAdd(cnt_dst + (size_t)r2 * N + dv.z, 1);
    int rk3 = atomicAdd(cnt_dst + (size_t)r3 * N + dv.w, 1);
    *(int4*)(rank + j) = make_int4(rk0, rk1, rk2, rk3);
}

// scan_block (SB blocks) || norm (remaining blocks)
__global__ void scan_norm(const int* __restrict__ counts, int* __restrict__ out,
                          int* __restrict__ blk_sums, int n, int SB,
                          const int* __restrict__ cnt, float* __restrict__ nrm, long nnorm) {
    if ((int)blockIdx.x < SB) {
        __shared__ int sh[256];
        int i = blockIdx.x * 256 + threadIdx.x;
        int v = (i < n) ? counts[i] : 0;
        sh[threadIdx.x] = v;
        __syncthreads();
#pragma unroll
        for (int off = 1; off < 256; off <<= 1) {
            int t = (threadIdx.x >= off) ? sh[threadIdx.x - off] : 0;
            __syncthreads();
            sh[threadIdx.x] += t;
            __syncthreads();
        }
        if (i < n) out[i] = sh[threadIdx.x] - v;
        if (threadIdx.x == 255) blk_sums[blockIdx.x] = sh[255];
    } else {
        long i = (long)(blockIdx.x - SB) * 256 + threadIdx.x;
        if (i < nnorm) nrm[i] = rsqrtf(fmaxf((float)cnt[i], 1.0f));
    }
}

__global__ void scan_sums(int* __restrict__ bs, int nb) {
    __shared__ int sh[256];
    __shared__ int carry;
    if (threadIdx.x == 0) carry = 0;
    __syncthreads();
    for (int base = 0; base < nb; base += 256) {
        int i = base + threadIdx.x;
        int v = (i < nb) ? bs[i] : 0;
        sh[threadIdx.x] = v;
        __syncthreads();
#pragma unroll
        for (int off = 1; off < 256; off <<= 1) {
            int t = (threadIdx.x >= off) ? sh[threadIdx.x - off] : 0;
            __syncthreads();
            sh[threadIdx.x] += t;
            __syncthreads();
        }
        if (i < nb) bs[i] = sh[threadIdx.x] - v + carry;  // exclusive
        int tot = sh[255];
        __syncthreads();
        if (threadIdx.x == 255) carry += tot;
        __syncthreads();
    }
}

__global__ void scan_add(int* __restrict__ out, const int* __restrict__ blk_sums,
                         int n, int total) {
    int i = blockIdx.x * 256 + threadIdx.x;
    if (i < n) out[i] += blk_sums[blockIdx.x];
    if (i == n - 1) out[n] = total;
}

// atomic-free fill, 4 edges/thread: pos = row_ptr[r][dst] + rank.
__global__ void fill_kernel(const int* __restrict__ src, const int* __restrict__ dst,
                            const float* __restrict__ nsrc, const int* __restrict__ row_ptr,
                            const int* __restrict__ rank, int2* __restrict__ e_pack,
                            int E, int N) {
    int i = blockIdx.x * blockDim.x + threadIdx.x;
    int j = i * 4;
    if (j >= RELS * E) return;
    int4 sv = *(const int4*)(src + j);
    int4 dv = *(const int4*)(dst + j);
    int4 rk = *(const int4*)(rank + j);
    int r0 = j / E, r1 = (j + 1) / E, r2 = (j + 2) / E, r3 = (j + 3) / E;
    int pos0 = row_ptr[(size_t)r0 * N + dv.x] + rk.x;
    int pos1 = row_ptr[(size_t)r1 * N + dv.y] + rk.y;
    int pos2 = row_ptr[(size_t)r2 * N + dv.z] + rk.z;
    int pos3 = row_ptr[(size_t)r3 * N + dv.w] + rk.w;
    e_pack[pos0] = make_int2(sv.x, __float_as_int(nsrc[(size_t)r0 * N + sv.x]));
    e_pack[pos1] = make_int2(sv.y, __float_as_int(nsrc[(size_t)r1 * N + sv.y]));
    e_pack[pos2] = make_int2(sv.z, __float_as_int(nsrc[(size_t)r2 * N + sv.z]));
    e_pack[pos3] = make_int2(sv.w, __float_as_int(nsrc[(size_t)r3 * N + sv.w]));
}

// ---- fused prep: cnt zero, x->bf16, W1^T, W2^T, bias sums --------------------

__global__ void prep_fused(const float* __restrict__ x, const float* __restrict__ W1,
                           const float* __restrict__ W2, const float* __restrict__ b1,
                           const float* __restrict__ b2,
                           unsigned short* __restrict__ x_bf, unsigned short* __restrict__ w1t,
                           unsigned short* __restrict__ w2t,
                           float* __restrict__ b1s, float* __restrict__ b2s,
                           int4* __restrict__ cnt_zero, long nz, long n8x) {
    const int T1 = RELS * DIN * DHID;
    const int T2 = RELS * DHID * DOUT;
    long i = blockIdx.x * (long)blockDim.x + threadIdx.x;
    if (i < nz) {
        cnt_zero[i] = make_int4(0, 0, 0, 0);
        return;
    }
    i -= nz;
    if (i < n8x) {
        const float4* ip = (const float4*)(x + i * 8);
        float4 v0 = ip[0], v1 = ip[1];
        ushort4 o0 = make_ushort4(f2bf(v0.x), f2bf(v0.y), f2bf(v0.z), f2bf(v0.w));
        ushort4 o1 = make_ushort4(f2bf(v1.x), f2bf(v1.y), f2bf(v1.z), f2bf(v1.w));
        ushort4* op = (ushort4*)(x_bf + i * 8);
        op[0] = o0; op[1] = o1;
    } else if (i < n8x + T1) {
        int j = (int)(i - n8x);
        int r = j / (DIN * DHID);
        int rem = j - r * (DIN * DHID);
        int k = rem / DHID, n = rem - k * DHID;
        w1t[(size_t)n * (RELS * DIN) + r * DIN + k] = f2bf(W1[j]);
    } else if (i < n8x + T1 + T2) {
        int j = (int)(i - n8x - T1);
        int r = j / (DHID * DOUT);
        int rem = j - r * (DHID * DOUT);
        int k = rem / DOUT, n = rem - k * DOUT;
        w2t[((size_t)r * DOUT + n) * DHID + k] = f2bf(W2[j]);
    } else if (i < n8x + T1 + T2 + DHID + DOUT) {
        int c = (int)(i - n8x - T1 - T2);
        if (c < DHID) {
            b1s[c] = b1[c] + b1[DHID + c] + b1[2 * DHID + c] + b1[3 * DHID + c];
        } else {
            int cc = c - DHID;
            b2s[cc] = b2[cc] + b2[DOUT + cc] + b2[2 * DOUT + cc] + b2[3 * DOUT + cc];
        }
    }
}

// ---- gload helper -----------------------------------------------------------

__device__ __forceinline__ void gload_lds16(const void* g, void* l) {
    __builtin_amdgcn_global_load_lds(
        (const __attribute__((address_space(1))) void*)g,
        (__attribute__((address_space(3))) void*)l, 16, 0, 0);
}

// ---- FUSED layer 1 (occupancy-fixed): BM=64, 512 thr, 4 blocks/CU ----------
// Per rel: 8 waves x 8 rows gather x into LDS [64][264] -> barrier ->
// MFMA K=256 (A from LDS, B from L2-hot w1t) -> barrier. Accumulate over rels.
// Epilogue: bias+relu -> h_bf. No agg4 round-trip.

__global__ __launch_bounds__(512, 8) void fused1(
    const unsigned short* __restrict__ x_bf, const int* __restrict__ rp,
    const int2* __restrict__ e_pack, const float* __restrict__ ndst,
    const unsigned short* __restrict__ w1t, const float* __restrict__ b1s,
    unsigned short* __restrict__ h_bf, int N) {
    __shared__ __align__(16) unsigned short smA[64 * LDP];   // 33.8 KB
    const int tid = threadIdx.x;
    const int lane = tid & 63;
    const int wid = tid >> 6;           // 0..7
    const int wr = wid >> 2, wc = wid & 3;
    const int brow = blockIdx.x * 64;
    const int s = lane >> 4, rl = lane & 15;
    const int h = lane >> 5, l = lane & 31;

    f32x4 acc[2][4] = {};

    for (int r = 0; r < RELS; ++r) {
        // ---- gather phase: this wave owns rows wid*8 .. wid*8+7
        for (int t = 0; t < 8; ++t) {
            int row = wid * 8 + t;
            int node = brow + row;
            int beg = 0, end = 0;
            float nd = 0.f;
            if (node < N) {
                size_t base = (size_t)r * N + node;
                beg = rp[base]; end = rp[base + 1];
                nd = ndst[base];
            }
            float acc0[8] = {}, acc1[8] = {};
            int e = beg + h;
            for (; e + 2 < end; e += 4) {
                int2 p0 = e_pack[e];
                int2 p1 = e_pack[e + 2];
                uint4v u0 = *(const uint4v*)(x_bf + (size_t)p0.x * DIN + l * 8);
                uint4v u1 = *(const uint4v*)(x_bf + (size_t)p1.x * DIN + l * 8);
                float ns0 = __int_as_float(p0.y);
                float ns1 = __int_as_float(p1.y);
#pragma unroll
                for (int q = 0; q < 4; ++q) {
                    acc0[2 * q]     += ns0 * __uint_as_float(u0[q] << 16);
                    acc0[2 * q + 1] += ns0 * __uint_as_float(u0[q] & 0xffff0000u);
                    acc1[2 * q]     += ns1 * __uint_as_float(u1[q] << 16);
                    acc1[2 * q + 1] += ns1 * __uint_as_float(u1[q] & 0xffff0000u);
                }
            }
            if (e < end) {
                int2 p0 = e_pack[e];
                uint4v u0 = *(const uint4v*)(x_bf + (size_t)p0.x * DIN + l * 8);
                float ns0 = __int_as_float(p0.y);
#pragma unroll
                for (int q = 0; q < 4; ++q) {
                    acc0[2 * q]     += ns0 * __uint_as_float(u0[q] << 16);
                    acc0[2 * q + 1] += ns0 * __uint_as_float(u0[q] & 0xffff0000u);
                }
            }
            uint4v o;
#pragma unroll
            for (int q = 0; q < 4; ++q) {
                float a = acc0[2 * q] + acc1[2 * q];
                float b = acc0[2 * q + 1] + acc1[2 * q + 1];
                a += __shfl_xor(a, 32);
                b += __shfl_xor(b, 32);
                o[q] = cvt_pk_bf16(nd * a, nd * b);
            }
            if (h == 0)
                *(uint4v*)(smA + (size_t)row * LDP + l * 8) = o;
        }
        __syncthreads();

        // ---- MFMA phase: K=256 of this rel (A from LDS, B from w1t)
        const unsigned short* wb = w1t + (size_t)r * DIN;
#pragma unroll 2
        for (int k0 = 0; k0 < 256; k0 += 32) {
            short8 a[2], b[4];
#pragma unroll
            for (int i = 0; i < 2; ++i) {
                int arow = wr * 32 + i * 16 + rl;
                a[i] = *(const short8*)(smA + (size_t)arow * LDP + k0 + s * 8);
            }
#pragma unroll
            for (int j = 0; j < 4; ++j) {
                int col = wc * 64 + j * 16 + rl;
                b[j] = *(const short8*)(wb + (size_t)col * (RELS * DIN) + k0 + s * 8);
            }
#pragma unroll
            for (int i = 0; i < 2; ++i)
#pragma unroll
                for (int j = 0; j < 4; ++j)
                    acc[i][j] = __builtin_amdgcn_mfma_f32_16x16x32_bf16(a[i], b[j], acc[i][j], 0, 0, 0);
        }
        __syncthreads();
    }

    // ---- epilogue: bias + relu -> h_bf [N][256]
    const int rq = lane >> 4;
#pragma unroll
    for (int i = 0; i < 2; ++i) {
        int rbase = brow + wr * 32 + i * 16 + rq * 4;
#pragma unroll
        for (int j = 0; j < 4; ++j) {
            int col = wc * 64 + j * 16 + rl;
            float bb = b1s[col];
#pragma unroll
            for (int t = 0; t < 4; ++t) {
                int row = rbase + t;
                if (row < N) h_bf[(size_t)row * DHID + col] = f2bf(fmaxf(acc[i][j][t] + bb, 0.f));
            }
        }
    }
}

// ---- gemm2_k256: [M,256] @ [512,256]^T (BN=256 halves) -> bf16 * nsrc -------

__global__ __launch_bounds__(512) void gemm2_k256(
    const unsigned short* __restrict__ A, const unsigned short* __restrict__ Bt,
    unsigned short* __restrict__ C, int M,
    const float* __restrict__ nsrc_all, int Nnodes) {
    __shared__ unsigned short smA[128 * 32];
    __shared__ unsigned short smB[256 * 32];
    const int tid = threadIdx.x;
    const int lane = tid & 63;
    const int wid = tid >> 6;
    const int wr = wid >> 2, wc = wid & 3;
    const int brow = blockIdx.x * 128;
    const int bcol = blockIdx.y * 256;
    const int K = DHID;   // 256

    f32x4 acc[4][4] = {};
    const int s = lane >> 4;
    const int rl = lane & 15;

    for (int k0 = 0; k0 < K; k0 += 32) {
        {
            int c = tid;
            int cl = c ^ ((c >> 3) & 3);
            int row = cl >> 2, slot = cl & 3;
            int ga = brow + row; ga = ga < M ? ga : M - 1;
            size_t ldsoff = (size_t)(tid & ~63) * 16;
            gload_lds16(A + (size_t)ga * K + k0 + slot * 8, (char*)smA + ldsoff);
        }
#pragma unroll
        for (int q = 0; q < 2; ++q) {
            int c = q * 512 + tid;
            int cl = c ^ ((c >> 3) & 3);
            int row = cl >> 2, slot = cl & 3;
            size_t ldsoff = (size_t)(q * 512 + (tid & ~63)) * 16;
            gload_lds16(Bt + (size_t)(bcol + row) * K + k0 + slot * 8, (char*)smB + ldsoff);
        }
        asm volatile("s_waitcnt vmcnt(0)" ::: "memory");
        __syncthreads();

        short8 a[4], b[4];
#pragma unroll
        for (int i = 0; i < 4; ++i) {
            int r = wr * 64 + i * 16 + rl;
            int ch = r * 4 + (s ^ ((r >> 1) & 3));
            a[i] = *(const short8*)((const char*)smA + ch * 16);
        }
#pragma unroll
        for (int j = 0; j < 4; ++j) {
            int r = wc * 64 + j * 16 + rl;
            int ch = r * 4 + (s ^ ((r >> 1) & 3));
            b[j] = *(const short8*)((const char*)smB + ch * 16);
        }
#pragma unroll
        for (int i = 0; i < 4; ++i)
#pragma unroll
            for (int j = 0; j < 4; ++j)
                acc[i][j] = __builtin_amdgcn_mfma_f32_16x16x32_bf16(a[i], b[j], acc[i][j], 0, 0, 0);
        __syncthreads();
    }

    const int rq = lane >> 4;
#pragma unroll
    for (int i = 0; i < 4; ++i) {
        int rbase = brow + wr * 64 + i * 16 + rq * 4;
#pragma unroll
        for (int j = 0; j < 4; ++j) {
            int colg = bcol + wc * 64 + j * 16 + rl;
            const float* nsr = nsrc_all + (size_t)(colg >> 7) * Nnodes;
#pragma unroll
            for (int t = 0; t < 4; ++t) {
                int row = rbase + t;
                if (row < M)
                    C[(size_t)row * (RELS * DOUT) + colg] = f2bf(acc[i][j][t] * nsr[row]);
            }
        }
    }
}

// ---- layer-2 gather: QUARTER-wave per edge -----------------------------------

__global__ void gather2_fused(const unsigned short* __restrict__ hw4,
                              const int* __restrict__ rp, const int2* __restrict__ e_pack,
                              const float* __restrict__ ndst, const float* __restrict__ b2s,
                              float* __restrict__ out, int N) {
    int wid = (int)((blockIdx.x * (long)blockDim.x + threadIdx.x) >> 6);
    if (wid >= N) return;
    int lane = threadIdx.x & 63;
    int q = lane >> 4, l4 = lane & 15;
    float oacc[8] = {};
#pragma unroll
    for (int r = 0; r < RELS; ++r) {
        int beg = rp[(size_t)r * N + wid], end = rp[(size_t)r * N + wid + 1];
        float acc[8] = {};
        for (int e = beg + q; e < end; e += 4) {
            int s = e_pack[e].x;
            uint4v u = *(const uint4v*)(hw4 + (size_t)s * (RELS * DOUT) + r * DOUT + l4 * 8);
#pragma unroll
            for (int k = 0; k < 4; ++k) {
                acc[2 * k]     += __uint_as_float(u[k] << 16);
                acc[2 * k + 1] += __uint_as_float(u[k] & 0xffff0000u);
            }
        }
        float nd = ndst[(size_t)r * N + wid];
#pragma unroll
        for (int j = 0; j < 8; ++j) oacc[j] += nd * acc[j];
    }
#pragma unroll
    for (int j = 0; j < 8; ++j) {
        oacc[j] += __shfl_xor(oacc[j], 16);
        oacc[j] += __shfl_xor(oacc[j], 32);
    }
    if (q == 0) {
        f32x4 o0, o1;
#pragma unroll
        for (int k = 0; k < 4; ++k) o0[k] = oacc[k] + b2s[l4 * 8 + k];
#pragma unroll
        for (int k = 0; k < 4; ++k) o1[k] = oacc[4 + k] + b2s[l4 * 8 + 4 + k];
        __builtin_nontemporal_store(o0, (f32x4*)(out + (size_t)wid * DOUT + l4 * 8));
        __builtin_nontemporal_store(o1, (f32x4*)(out + (size_t)wid * DOUT + l4 * 8 + 4));
    }
}

// ---- launch ------------------------------------------------------------------

extern "C" void kernel_launch(void* const* d_in, const int* in_sizes, int n_in,
                              void* d_out, int out_size, void* d_ws, size_t ws_size,
                              hipStream_t stream) {
    const float* x   = (const float*)d_in[0];
    const int*   src = (const int*)d_in[1];
    const int*   dst = (const int*)d_in[2];
    const float* W1  = (const float*)d_in[3];
    const float* b1  = (const float*)d_in[4];
    const float* W2  = (const float*)d_in[5];
    const float* b2  = (const float*)d_in[6];
    float* out = (float*)d_out;

    const int N = in_sizes[0] / DIN;       // 100000
    const int E = in_sizes[1] / RELS;      // 400000
    const int RN = RELS * N;

    // Workspace layout (cnt tables 16B-aligned at base for int4 zeroing)
    char* p = (char*)d_ws;
    int*   cnt_src = (int*)p;    p += (size_t)RN * sizeof(int);
    int*   cnt_dst = (int*)p;    p += (size_t)RN * sizeof(int);       // contiguous after cnt_src
    float* nsrc    = (float*)p;  p += (size_t)RN * sizeof(float);
    float* ndst    = (float*)p;  p += (size_t)RN * sizeof(float);     // contiguous after nsrc
    int*   row_ptr = (int*)p;    p += ((size_t)RN + 16) * sizeof(int);
    int*   rank    = (int*)p;    p += (size_t)RELS * E * sizeof(int);
    int2*  e_pack  = (int2*)p;   p += (size_t)RELS * E * sizeof(int2);
    int*   blk_sums= (int*)p;    p += 2048 * sizeof(int);
    float* b1s     = (float*)p;  p += DHID * sizeof(float);
    float* b2s     = (float*)p;  p += DOUT * sizeof(float);
    unsigned short* x_bf = (unsigned short*)p; p += (size_t)N * DIN * sizeof(short);
    unsigned short* w1t  = (unsigned short*)p; p += (size_t)RELS * DIN * DHID * sizeof(short);
    unsigned short* w2t  = (unsigned short*)p; p += (size_t)RELS * DHID * DOUT * sizeof(short);
    unsigned short* h_bf = (unsigned short*)p; p += (size_t)N * DHID * sizeof(short);
    unsigned short* hw4  = (unsigned short*)p; p += (size_t)N * RELS * DOUT * sizeof(short);

    // 0) fused prep: zero cnt tables + x->bf16 + W transposes + bias sums
    const long n8x = (long)N * DIN / 8;
    const long nz = ((long)2 * RN + 3) / 4;   // int4 zero elements
    {
        long tot = nz + n8x + RELS * DIN * DHID + RELS * DHID * DOUT + DHID + DOUT;
        prep_fused<<<(int)((tot + 255) / 256), 256, 0, stream>>>(
            x, W1, W2, b1, b2, x_bf, w1t, w2t, b1s, b2s, (int4*)cnt_src, nz, n8x);
    }

    // 1) degree histograms + rank capture (4 edges/thread)
    {
        int quads = (RELS * E + 3) / 4;
        hist_kernel<<<(quads + 255) / 256, 256, 0, stream>>>(
            src, dst, cnt_src, cnt_dst, rank, E, N);
    }

    // 2) scan_block || norm, then scan_sums, scan_add
    const int nscan = (RN + 255) / 256;
    {
        long nnorm = (long)2 * RN;
        int NB = (int)((nnorm + 255) / 256);
        scan_norm<<<nscan + NB, 256, 0, stream>>>(
            cnt_dst, row_ptr, blk_sums, RN, nscan, cnt_src, nsrc, nnorm);
    }
    scan_sums<<<1, 256, 0, stream>>>(blk_sums, nscan);
    scan_add<<<nscan, 256, 0, stream>>>(row_ptr, blk_sums, RN, RELS * E);

    // 3) atomic-free fill (4 edges/thread)
    {
        int quads = (RELS * E + 3) / 4;
        fill_kernel<<<(quads + 255) / 256, 256, 0, stream>>>(
            src, dst, nsrc, row_ptr, rank, e_pack, E, N);
    }

    // 4) layer 1 FUSED (64-node blocks, 4 blocks/CU): gather+MFMA -> h_bf
    {
        int gx64 = (N + 63) / 64;
        fused1<<<gx64, 512, 0, stream>>>(x_bf, row_ptr, e_pack, ndst, w1t, b1s, h_bf, N);
    }

    // 5) layer 2 project-first: BN=256 GEMM (2 col-blocks, nsrc epilogue) + gather
    {
        const int gx = (N + 127) / 128;
        dim3 grid(gx, 2);
        gemm2_k256<<<grid, 512, 0, stream>>>(h_bf, w2t, hw4, N, nsrc, N);
        int gblocks = (N + 3) / 4;
        gather2_fused<<<gblocks, 256, 0, stream>>>(hw4, row_ptr, e_pack, ndst, b2s, out, N);
    }
}

// Round 20
// 671.552 us; speedup vs baseline: 1.1771x; 1.1771x over previous
//
#include <hip/hip_runtime.h>

// RGCN: 2-layer hetero GraphConv, R=4 relations.
// R12 (738): CSR+rank atomic-free fill, scan||norm, half-wave gathers,
// aggregate-first layer 1, concat GEMMs, NT-store not-soon-read outputs.
// R14 (699): hist ILP, gemm1_k1024 single-pass. R16 (688): gather2 quarter-wave,
// memset folded into prep. R17 (675, BEST): gemm2 BN=256, fill x4.
// R13/R18 both REGRESSED fusing gather1+gemm1 (occupancy trap at BM=128;
// L2-miss B-streaming + write-combine loss at BM=64) -> the agg4 round-trip
// is cheaper than fusion. R19: exact revert to R17.

#define RELS 4
#define DIN 256
#define DHID 256
#define DOUT 128

typedef short short8 __attribute__((ext_vector_type(8)));
typedef unsigned short ushort8 __attribute__((ext_vector_type(8)));
typedef float f32x4 __attribute__((ext_vector_type(4)));
typedef unsigned int uint4v __attribute__((ext_vector_type(4)));

// ---- helpers --------------------------------------------------------------

__device__ __forceinline__ unsigned short f2bf(float f) {
    unsigned int u = __float_as_uint(f);
    u += 0x7FFFu + ((u >> 16) & 1u);   // round-to-nearest-even
    return (unsigned short)(u >> 16);
}
__device__ __forceinline__ unsigned int cvt_pk_bf16(float lo, float hi) {
    unsigned int r;
    asm("v_cvt_pk_bf16_f32 %0, %1, %2" : "=v"(r) : "v"(lo), "v"(hi));
    return r;
}

// ---- CSR build --------------------------------------------------------------

// 4 edges per thread (int4 loads, 8 atomics in flight). Rank = dst-atomic's
// return value = unique slot in (rel,dst) segment (order-independent).
__global__ void hist_kernel(const int* __restrict__ src, const int* __restrict__ dst,
                            int* __restrict__ cnt_src, int* __restrict__ cnt_dst,
                            int* __restrict__ rank, int E, int N) {
    int i = blockIdx.x * blockDim.x + threadIdx.x;
    int j = i * 4;
    if (j >= RELS * E) return;
    int4 sv = *(const int4*)(src + j);
    int4 dv = *(const int4*)(dst + j);
    int r0 = j / E, r1 = (j + 1) / E, r2 = (j + 2) / E, r3 = (j + 3) / E;
    atomicAdd(cnt_src + (size_t)r0 * N + sv.x, 1);
    atomicAdd(cnt_src + (size_t)r1 * N + sv.y, 1);
    atomicAdd(cnt_src + (size_t)r2 * N + sv.z, 1);
    atomicAdd(cnt_src + (size_t)r3 * N + sv.w, 1);
    int rk0 = atomicAdd(cnt_dst + (size_t)r0 * N + dv.x, 1);
    int rk1 = atomicAdd(cnt_dst + (size_t)r1 * N + dv.y, 1);
    int rk2 = atomicAdd(cnt_dst + (size_t)r2 * N + dv.z, 1);
    int rk3 = atomicAdd(cnt_dst + (size_t)r3 * N + dv.w, 1);
    *(int4*)(rank + j) = make_int4(rk0, rk1, rk2, rk3);
}

// scan_block (SB blocks) || norm (remaining blocks)
__global__ void scan_norm(const int* __restrict__ counts, int* __restrict__ out,
                          int* __restrict__ blk_sums, int n, int SB,
                          const int* __restrict__ cnt, float* __restrict__ nrm, long nnorm) {
    if ((int)blockIdx.x < SB) {
        __shared__ int sh[256];
        int i = blockIdx.x * 256 + threadIdx.x;
        int v = (i < n) ? counts[i] : 0;
        sh[threadIdx.x] = v;
        __syncthreads();
#pragma unroll
        for (int off = 1; off < 256; off <<= 1) {
            int t = (threadIdx.x >= off) ? sh[threadIdx.x - off] : 0;
            __syncthreads();
            sh[threadIdx.x] += t;
            __syncthreads();
        }
        if (i < n) out[i] = sh[threadIdx.x] - v;
        if (threadIdx.x == 255) blk_sums[blockIdx.x] = sh[255];
    } else {
        long i = (long)(blockIdx.x - SB) * 256 + threadIdx.x;
        if (i < nnorm) nrm[i] = rsqrtf(fmaxf((float)cnt[i], 1.0f));
    }
}

__global__ void scan_sums(int* __restrict__ bs, int nb) {
    __shared__ int sh[256];
    __shared__ int carry;
    if (threadIdx.x == 0) carry = 0;
    __syncthreads();
    for (int base = 0; base < nb; base += 256) {
        int i = base + threadIdx.x;
        int v = (i < nb) ? bs[i] : 0;
        sh[threadIdx.x] = v;
        __syncthreads();
#pragma unroll
        for (int off = 1; off < 256; off <<= 1) {
            int t = (threadIdx.x >= off) ? sh[threadIdx.x - off] : 0;
            __syncthreads();
            sh[threadIdx.x] += t;
            __syncthreads();
        }
        if (i < nb) bs[i] = sh[threadIdx.x] - v + carry;  // exclusive
        int tot = sh[255];
        __syncthreads();
        if (threadIdx.x == 255) carry += tot;
        __syncthreads();
    }
}

__global__ void scan_add(int* __restrict__ out, const int* __restrict__ blk_sums,
                         int n, int total) {
    int i = blockIdx.x * 256 + threadIdx.x;
    if (i < n) out[i] += blk_sums[blockIdx.x];
    if (i == n - 1) out[n] = total;
}

// atomic-free fill, 4 edges/thread: pos = row_ptr[r][dst] + rank.
// Plain stores — e_pack is read by the very next kernels (keep L2-resident).
__global__ void fill_kernel(const int* __restrict__ src, const int* __restrict__ dst,
                            const float* __restrict__ nsrc, const int* __restrict__ row_ptr,
                            const int* __restrict__ rank, int2* __restrict__ e_pack,
                            int E, int N) {
    int i = blockIdx.x * blockDim.x + threadIdx.x;
    int j = i * 4;
    if (j >= RELS * E) return;
    int4 sv = *(const int4*)(src + j);
    int4 dv = *(const int4*)(dst + j);
    int4 rk = *(const int4*)(rank + j);
    int r0 = j / E, r1 = (j + 1) / E, r2 = (j + 2) / E, r3 = (j + 3) / E;
    int pos0 = row_ptr[(size_t)r0 * N + dv.x] + rk.x;
    int pos1 = row_ptr[(size_t)r1 * N + dv.y] + rk.y;
    int pos2 = row_ptr[(size_t)r2 * N + dv.z] + rk.z;
    int pos3 = row_ptr[(size_t)r3 * N + dv.w] + rk.w;
    e_pack[pos0] = make_int2(sv.x, __float_as_int(nsrc[(size_t)r0 * N + sv.x]));
    e_pack[pos1] = make_int2(sv.y, __float_as_int(nsrc[(size_t)r1 * N + sv.y]));
    e_pack[pos2] = make_int2(sv.z, __float_as_int(nsrc[(size_t)r2 * N + sv.z]));
    e_pack[pos3] = make_int2(sv.w, __float_as_int(nsrc[(size_t)r3 * N + sv.w]));
}

// ---- fused prep: cnt zero, x->bf16, W1^T, W2^T, bias sums --------------------

__global__ void prep_fused(const float* __restrict__ x, const float* __restrict__ W1,
                           const float* __restrict__ W2, const float* __restrict__ b1,
                           const float* __restrict__ b2,
                           unsigned short* __restrict__ x_bf, unsigned short* __restrict__ w1t,
                           unsigned short* __restrict__ w2t,
                           float* __restrict__ b1s, float* __restrict__ b2s,
                           int4* __restrict__ cnt_zero, long nz, long n8x) {
    const int T1 = RELS * DIN * DHID;
    const int T2 = RELS * DHID * DOUT;
    long i = blockIdx.x * (long)blockDim.x + threadIdx.x;
    if (i < nz) {
        cnt_zero[i] = make_int4(0, 0, 0, 0);
        return;
    }
    i -= nz;
    if (i < n8x) {
        const float4* ip = (const float4*)(x + i * 8);
        float4 v0 = ip[0], v1 = ip[1];
        ushort4 o0 = make_ushort4(f2bf(v0.x), f2bf(v0.y), f2bf(v0.z), f2bf(v0.w));
        ushort4 o1 = make_ushort4(f2bf(v1.x), f2bf(v1.y), f2bf(v1.z), f2bf(v1.w));
        ushort4* op = (ushort4*)(x_bf + i * 8);
        op[0] = o0; op[1] = o1;
    } else if (i < n8x + T1) {
        int j = (int)(i - n8x);
        int r = j / (DIN * DHID);
        int rem = j - r * (DIN * DHID);
        int k = rem / DHID, n = rem - k * DHID;
        w1t[(size_t)n * (RELS * DIN) + r * DIN + k] = f2bf(W1[j]);
    } else if (i < n8x + T1 + T2) {
        int j = (int)(i - n8x - T1);
        int r = j / (DHID * DOUT);
        int rem = j - r * (DHID * DOUT);
        int k = rem / DOUT, n = rem - k * DOUT;
        w2t[((size_t)r * DOUT + n) * DHID + k] = f2bf(W2[j]);
    } else if (i < n8x + T1 + T2 + DHID + DOUT) {
        int c = (int)(i - n8x - T1 - T2);
        if (c < DHID) {
            b1s[c] = b1[c] + b1[DHID + c] + b1[2 * DHID + c] + b1[3 * DHID + c];
        } else {
            int cc = c - DHID;
            b2s[cc] = b2[cc] + b2[DOUT + cc] + b2[2 * DOUT + cc] + b2[3 * DOUT + cc];
        }
    }
}

// ---- gload helper -----------------------------------------------------------

__device__ __forceinline__ void gload_lds16(const void* g, void* l) {
    __builtin_amdgcn_global_load_lds(
        (const __attribute__((address_space(1))) void*)g,
        (__attribute__((address_space(3))) void*)l, 16, 0, 0);
}

// ---- gemm1_k1024: [M,1024] @ [1024,256]^T -> bf16 relu(.+bias), BN=256 ------

__global__ __launch_bounds__(512) void gemm1_k1024(
    const unsigned short* __restrict__ A, const unsigned short* __restrict__ Bt,
    unsigned short* __restrict__ C, int M, const float* __restrict__ b1s) {
    __shared__ unsigned short smA[128 * 32];
    __shared__ unsigned short smB[256 * 32];
    const int tid = threadIdx.x;
    const int lane = tid & 63;
    const int wid = tid >> 6;
    const int wr = wid >> 2, wc = wid & 3;
    const int brow = blockIdx.x * 128;
    const int K = RELS * DIN;   // 1024

    f32x4 acc[4][4] = {};
    const int s = lane >> 4;
    const int rl = lane & 15;

    for (int k0 = 0; k0 < K; k0 += 32) {
        {
            int c = tid;
            int cl = c ^ ((c >> 3) & 3);
            int row = cl >> 2, slot = cl & 3;
            int ga = brow + row; ga = ga < M ? ga : M - 1;
            size_t ldsoff = (size_t)(tid & ~63) * 16;
            gload_lds16(A + (size_t)ga * K + k0 + slot * 8, (char*)smA + ldsoff);
        }
#pragma unroll
        for (int q = 0; q < 2; ++q) {
            int c = q * 512 + tid;
            int cl = c ^ ((c >> 3) & 3);
            int row = cl >> 2, slot = cl & 3;
            size_t ldsoff = (size_t)(q * 512 + (tid & ~63)) * 16;
            gload_lds16(Bt + (size_t)row * K + k0 + slot * 8, (char*)smB + ldsoff);
        }
        asm volatile("s_waitcnt vmcnt(0)" ::: "memory");
        __syncthreads();

        short8 a[4], b[4];
#pragma unroll
        for (int i = 0; i < 4; ++i) {
            int r = wr * 64 + i * 16 + rl;
            int ch = r * 4 + (s ^ ((r >> 1) & 3));
            a[i] = *(const short8*)((const char*)smA + ch * 16);
        }
#pragma unroll
        for (int j = 0; j < 4; ++j) {
            int r = wc * 64 + j * 16 + rl;
            int ch = r * 4 + (s ^ ((r >> 1) & 3));
            b[j] = *(const short8*)((const char*)smB + ch * 16);
        }
#pragma unroll
        for (int i = 0; i < 4; ++i)
#pragma unroll
            for (int j = 0; j < 4; ++j)
                acc[i][j] = __builtin_amdgcn_mfma_f32_16x16x32_bf16(a[i], b[j], acc[i][j], 0, 0, 0);
        __syncthreads();
    }

    const int rq = lane >> 4;
#pragma unroll
    for (int i = 0; i < 4; ++i) {
        int rbase = brow + wr * 64 + i * 16 + rq * 4;
#pragma unroll
        for (int j = 0; j < 4; ++j) {
            int col = wc * 64 + j * 16 + rl;
            float bb = b1s[col];
#pragma unroll
            for (int t = 0; t < 4; ++t) {
                int row = rbase + t;
                if (row < M) C[(size_t)row * DHID + col] = f2bf(fmaxf(acc[i][j][t] + bb, 0.f));
            }
        }
    }
}

// ---- gemm2_k256: [M,256] @ [512,256]^T (BN=256 halves) -> bf16 * nsrc -------
// grid (gx, 2); 512 threads (8 waves 2x4), wave tile 64x64, K=256.

__global__ __launch_bounds__(512) void gemm2_k256(
    const unsigned short* __restrict__ A, const unsigned short* __restrict__ Bt,
    unsigned short* __restrict__ C, int M,
    const float* __restrict__ nsrc_all, int Nnodes) {
    __shared__ unsigned short smA[128 * 32];
    __shared__ unsigned short smB[256 * 32];
    const int tid = threadIdx.x;
    const int lane = tid & 63;
    const int wid = tid >> 6;
    const int wr = wid >> 2, wc = wid & 3;
    const int brow = blockIdx.x * 128;
    const int bcol = blockIdx.y * 256;
    const int K = DHID;   // 256

    f32x4 acc[4][4] = {};
    const int s = lane >> 4;
    const int rl = lane & 15;

    for (int k0 = 0; k0 < K; k0 += 32) {
        {
            int c = tid;
            int cl = c ^ ((c >> 3) & 3);
            int row = cl >> 2, slot = cl & 3;
            int ga = brow + row; ga = ga < M ? ga : M - 1;
            size_t ldsoff = (size_t)(tid & ~63) * 16;
            gload_lds16(A + (size_t)ga * K + k0 + slot * 8, (char*)smA + ldsoff);
        }
#pragma unroll
        for (int q = 0; q < 2; ++q) {
            int c = q * 512 + tid;
            int cl = c ^ ((c >> 3) & 3);
            int row = cl >> 2, slot = cl & 3;
            size_t ldsoff = (size_t)(q * 512 + (tid & ~63)) * 16;
            gload_lds16(Bt + (size_t)(bcol + row) * K + k0 + slot * 8, (char*)smB + ldsoff);
        }
        asm volatile("s_waitcnt vmcnt(0)" ::: "memory");
        __syncthreads();

        short8 a[4], b[4];
#pragma unroll
        for (int i = 0; i < 4; ++i) {
            int r = wr * 64 + i * 16 + rl;
            int ch = r * 4 + (s ^ ((r >> 1) & 3));
            a[i] = *(const short8*)((const char*)smA + ch * 16);
        }
#pragma unroll
        for (int j = 0; j < 4; ++j) {
            int r = wc * 64 + j * 16 + rl;
            int ch = r * 4 + (s ^ ((r >> 1) & 3));
            b[j] = *(const short8*)((const char*)smB + ch * 16);
        }
#pragma unroll
        for (int i = 0; i < 4; ++i)
#pragma unroll
            for (int j = 0; j < 4; ++j)
                acc[i][j] = __builtin_amdgcn_mfma_f32_16x16x32_bf16(a[i], b[j], acc[i][j], 0, 0, 0);
        __syncthreads();
    }

    const int rq = lane >> 4;
#pragma unroll
    for (int i = 0; i < 4; ++i) {
        int rbase = brow + wr * 64 + i * 16 + rq * 4;
#pragma unroll
        for (int j = 0; j < 4; ++j) {
            int colg = bcol + wc * 64 + j * 16 + rl;
            const float* nsr = nsrc_all + (size_t)(colg >> 7) * Nnodes;
#pragma unroll
            for (int t = 0; t < 4; ++t) {
                int row = rbase + t;
                if (row < M)
                    C[(size_t)row * (RELS * DOUT) + colg] = f2bf(acc[i][j][t] * nsr[row]);
            }
        }
    }
}

// ---- gathers ----------------------------------------------------------------

// layer 1 aggregate-first: one wave per (node, relation); HALF-WAVE per edge
// (x row = 512B = 32 lanes x 16B). uint pair-extraction, cvt_pk epilogue.
__global__ void gather1_agg(const unsigned short* __restrict__ x_bf,
                            const int* __restrict__ rp, const int2* __restrict__ e_pack,
                            const float* __restrict__ ndst,
                            unsigned short* __restrict__ agg4, int N) {
    long w = (blockIdx.x * (long)blockDim.x + threadIdx.x) >> 6;
    int d = (int)(w >> 2);
    if (d >= N) return;
    int r = (int)(w & 3);
    int lane = threadIdx.x & 63;
    int h = lane >> 5, l = lane & 31;
    int beg = rp[(size_t)r * N + d], end = rp[(size_t)r * N + d + 1];
    float acc0[8] = {}, acc1[8] = {};
    int e = beg + h;
    for (; e + 2 < end; e += 4) {     // this half's edges: e, e+2
        int2 p0 = e_pack[e];
        int2 p1 = e_pack[e + 2];
        uint4v u0 = *(const uint4v*)(x_bf + (size_t)p0.x * DIN + l * 8);
        uint4v u1 = *(const uint4v*)(x_bf + (size_t)p1.x * DIN + l * 8);
        float ns0 = __int_as_float(p0.y);
        float ns1 = __int_as_float(p1.y);
#pragma unroll
        for (int q = 0; q < 4; ++q) {
            acc0[2 * q]     += ns0 * __uint_as_float(u0[q] << 16);
            acc0[2 * q + 1] += ns0 * __uint_as_float(u0[q] & 0xffff0000u);
            acc1[2 * q]     += ns1 * __uint_as_float(u1[q] << 16);
            acc1[2 * q + 1] += ns1 * __uint_as_float(u1[q] & 0xffff0000u);
        }
    }
    if (e < end) {
        int2 p0 = e_pack[e];
        uint4v u0 = *(const uint4v*)(x_bf + (size_t)p0.x * DIN + l * 8);
        float ns0 = __int_as_float(p0.y);
#pragma unroll
        for (int q = 0; q < 4; ++q) {
            acc0[2 * q]     += ns0 * __uint_as_float(u0[q] << 16);
            acc0[2 * q + 1] += ns0 * __uint_as_float(u0[q] & 0xffff0000u);
        }
    }
    float nd = ndst[(size_t)r * N + d];
    uint4v o;
#pragma unroll
    for (int q = 0; q < 4; ++q) {
        float a = acc0[2 * q] + acc1[2 * q];
        float b = acc0[2 * q + 1] + acc1[2 * q + 1];
        a += __shfl_xor(a, 32);
        b += __shfl_xor(b, 32);
        o[q] = cvt_pk_bf16(nd * a, nd * b);
    }
    if (h == 0)
        __builtin_nontemporal_store(o, (uint4v*)(agg4 + (size_t)d * (RELS * DIN) + r * DIN + l * 8));
}

// layer 2 project-first: one wave per dst node; QUARTER-WAVE per edge
// (hw4 row slice = 256B = 16 lanes x 16B). 4 edges in flight per wave.
__global__ void gather2_fused(const unsigned short* __restrict__ hw4,
                              const int* __restrict__ rp, const int2* __restrict__ e_pack,
                              const float* __restrict__ ndst, const float* __restrict__ b2s,
                              float* __restrict__ out, int N) {
    int wid = (int)((blockIdx.x * (long)blockDim.x + threadIdx.x) >> 6);
    if (wid >= N) return;
    int lane = threadIdx.x & 63;
    int q = lane >> 4, l4 = lane & 15;
    float oacc[8] = {};
#pragma unroll
    for (int r = 0; r < RELS; ++r) {
        int beg = rp[(size_t)r * N + wid], end = rp[(size_t)r * N + wid + 1];
        float acc[8] = {};
        for (int e = beg + q; e < end; e += 4) {
            int s = e_pack[e].x;
            uint4v u = *(const uint4v*)(hw4 + (size_t)s * (RELS * DOUT) + r * DOUT + l4 * 8);
#pragma unroll
            for (int k = 0; k < 4; ++k) {
                acc[2 * k]     += __uint_as_float(u[k] << 16);
                acc[2 * k + 1] += __uint_as_float(u[k] & 0xffff0000u);
            }
        }
        float nd = ndst[(size_t)r * N + wid];
#pragma unroll
        for (int j = 0; j < 8; ++j) oacc[j] += nd * acc[j];
    }
#pragma unroll
    for (int j = 0; j < 8; ++j) {
        oacc[j] += __shfl_xor(oacc[j], 16);
        oacc[j] += __shfl_xor(oacc[j], 32);
    }
    if (q == 0) {
        f32x4 o0, o1;
#pragma unroll
        for (int k = 0; k < 4; ++k) o0[k] = oacc[k] + b2s[l4 * 8 + k];
#pragma unroll
        for (int k = 0; k < 4; ++k) o1[k] = oacc[4 + k] + b2s[l4 * 8 + 4 + k];
        __builtin_nontemporal_store(o0, (f32x4*)(out + (size_t)wid * DOUT + l4 * 8));
        __builtin_nontemporal_store(o1, (f32x4*)(out + (size_t)wid * DOUT + l4 * 8 + 4));
    }
}

// ---- launch ------------------------------------------------------------------

extern "C" void kernel_launch(void* const* d_in, const int* in_sizes, int n_in,
                              void* d_out, int out_size, void* d_ws, size_t ws_size,
                              hipStream_t stream) {
    const float* x   = (const float*)d_in[0];
    const int*   src = (const int*)d_in[1];
    const int*   dst = (const int*)d_in[2];
    const float* W1  = (const float*)d_in[3];
    const float* b1  = (const float*)d_in[4];
    const float* W2  = (const float*)d_in[5];
    const float* b2  = (const float*)d_in[6];
    float* out = (float*)d_out;

    const int N = in_sizes[0] / DIN;       // 100000
    const int E = in_sizes[1] / RELS;      // 400000
    const int RN = RELS * N;

    // Workspace layout (cnt tables 16B-aligned at base for int4 zeroing)
    char* p = (char*)d_ws;
    int*   cnt_src = (int*)p;    p += (size_t)RN * sizeof(int);
    int*   cnt_dst = (int*)p;    p += (size_t)RN * sizeof(int);       // contiguous after cnt_src
    float* nsrc    = (float*)p;  p += (size_t)RN * sizeof(float);
    float* ndst    = (float*)p;  p += (size_t)RN * sizeof(float);     // contiguous after nsrc
    int*   row_ptr = (int*)p;    p += ((size_t)RN + 16) * sizeof(int);
    int*   rank    = (int*)p;    p += (size_t)RELS * E * sizeof(int);
    int2*  e_pack  = (int2*)p;   p += (size_t)RELS * E * sizeof(int2);
    int*   blk_sums= (int*)p;    p += 2048 * sizeof(int);
    float* b1s     = (float*)p;  p += DHID * sizeof(float);
    float* b2s     = (float*)p;  p += DOUT * sizeof(float);
    unsigned short* x_bf = (unsigned short*)p; p += (size_t)N * DIN * sizeof(short);
    unsigned short* w1t  = (unsigned short*)p; p += (size_t)RELS * DIN * DHID * sizeof(short);
    unsigned short* w2t  = (unsigned short*)p; p += (size_t)RELS * DHID * DOUT * sizeof(short);
    unsigned short* h_bf = (unsigned short*)p; p += (size_t)N * DHID * sizeof(short);
    unsigned short* agg4 = (unsigned short*)p; p += (size_t)N * RELS * DIN * sizeof(short);
    unsigned short* hw4  = agg4;   // alias: agg4 dead after gemm1

    // 0) fused prep: zero cnt tables + x->bf16 + W transposes + bias sums
    const long n8x = (long)N * DIN / 8;
    const long nz = ((long)2 * RN + 3) / 4;   // int4 zero elements
    {
        long tot = nz + n8x + RELS * DIN * DHID + RELS * DHID * DOUT + DHID + DOUT;
        prep_fused<<<(int)((tot + 255) / 256), 256, 0, stream>>>(
            x, W1, W2, b1, b2, x_bf, w1t, w2t, b1s, b2s, (int4*)cnt_src, nz, n8x);
    }

    // 1) degree histograms + rank capture (4 edges/thread)
    {
        int quads = (RELS * E + 3) / 4;
        hist_kernel<<<(quads + 255) / 256, 256, 0, stream>>>(
            src, dst, cnt_src, cnt_dst, rank, E, N);
    }

    // 2) scan_block || norm, then scan_sums, scan_add
    const int nscan = (RN + 255) / 256;
    {
        long nnorm = (long)2 * RN;
        int NB = (int)((nnorm + 255) / 256);
        scan_norm<<<nscan + NB, 256, 0, stream>>>(
            cnt_dst, row_ptr, blk_sums, RN, nscan, cnt_src, nsrc, nnorm);
    }
    scan_sums<<<1, 256, 0, stream>>>(blk_sums, nscan);
    scan_add<<<nscan, 256, 0, stream>>>(row_ptr, blk_sums, RN, RELS * E);

    // 3) atomic-free fill (4 edges/thread)
    {
        int quads = (RELS * E + 3) / 4;
        fill_kernel<<<(quads + 255) / 256, 256, 0, stream>>>(
            src, dst, nsrc, row_ptr, rank, e_pack, E, N);
    }

    const int gx = (N + 127) / 128;

    // 4) layer 1 aggregate-first: gather x -> agg4 [N][1024], then BN=256
    //    single-pass K=1024 GEMM with bias+relu epilogue -> h_bf
    {
        long waves = (long)RELS * N;
        int blocks = (int)((waves + 3) / 4);
        gather1_agg<<<blocks, 256, 0, stream>>>(x_bf, row_ptr, e_pack, ndst, agg4, N);
        gemm1_k1024<<<gx, 512, 0, stream>>>(agg4, w1t, h_bf, N, b1s);
    }

    // 5) layer 2 project-first: BN=256 GEMM (2 col-blocks, nsrc epilogue) + gather
    {
        dim3 grid(gx, 2);
        gemm2_k256<<<grid, 512, 0, stream>>>(h_bf, w2t, hw4, N, nsrc, N);
        int gblocks = (N + 3) / 4;
        gather2_fused<<<gblocks, 256, 0, stream>>>(hw4, row_ptr, e_pack, ndst, b2s, out, N);
    }
}